// Round 1
// baseline (272.475 us; speedup 1.0000x reference)
//
#include <hip/hip_runtime.h>
#include <cstdint>
#include <cstddef>

#define BATCH 2048
#define NZ 128
#define NGEN 8
#define SPB 4                       // samples per block (same generator)
#define NBLK (BATCH / SPB + NGEN)   // 520: covers worst-case per-generator padding

typedef unsigned int u32;
typedef unsigned short u16;

__device__ __forceinline__ float lrelu(float x) { return fmaxf(x, 0.2f * x); }
__device__ __forceinline__ float bflo(u32 u) { union { u32 i; float f; } v; v.i = u << 16; return v.f; }
__device__ __forceinline__ float bfhi(u32 u) { union { u32 i; float f; } v; v.i = u & 0xffff0000u; return v.f; }
__device__ __forceinline__ float bf1(u16 u) { union { u32 i; float f; } v; v.i = ((u32)u) << 16; return v.f; }
__device__ __forceinline__ u16 f2bf(float f) {
    union { float f; u32 i; } v; v.f = f;
    u32 r = v.i + 0x7fffu + ((v.i >> 16) & 1u);   // round-to-nearest-even
    return (u16)(r >> 16);
}
__device__ __forceinline__ void unpack8(const u16* p, float* r) {
    const uint4 q = *(const uint4*)p;
    r[0] = bflo(q.x); r[1] = bfhi(q.x); r[2] = bflo(q.y); r[3] = bfhi(q.y);
    r[4] = bflo(q.z); r[5] = bfhi(q.z); r[6] = bflo(q.w); r[7] = bfhi(q.w);
}

// ---------------------------------------------------------------------------
// Kernel 1: bin samples by generator into ws. Layout (ints):
//   wsi[0]            = total padded count
//   wsi[16 .. 16+tot) = sample ids grouped by generator, each group padded to
//                       a multiple of SPB with -1 sentinels.
// ---------------------------------------------------------------------------
__global__ void bin_kernel(const int* __restrict__ g_idx, int* __restrict__ wsi) {
    __shared__ int cnt[NGEN];
    __shared__ int pbase[NGEN + 1];
    __shared__ u16 rank[BATCH];
    const int tid = threadIdx.x;
    if (tid < NGEN) cnt[tid] = 0;
    __syncthreads();
    for (int b = tid; b < BATCH; b += 256) {
        int g = g_idx[b];
        rank[b] = (u16)atomicAdd(&cnt[g], 1);
    }
    __syncthreads();
    if (tid == 0) {
        int acc = 0;
        for (int g = 0; g < NGEN; ++g) {
            pbase[g] = acc;
            acc += ((cnt[g] + SPB - 1) / SPB) * SPB;
        }
        pbase[NGEN] = acc;
        wsi[0] = acc;
    }
    __syncthreads();
    const int total = pbase[NGEN];
    for (int i = tid; i < total; i += 256) wsi[16 + i] = -1;
    __syncthreads();
    for (int b = tid; b < BATCH; b += 256) {
        int g = g_idx[b];
        wsi[16 + pbase[g] + (int)rank[b]] = b;
    }
}

// ---------------------------------------------------------------------------
// Kernel 2: full generator pipeline for SPB samples sharing one generator.
// All transposed convs have effective pad=1 (the reference's pad arg is the
// conv-side padding k-1-p): 7 -> 14 -> 28 -> 28.
// out[co,y,x] = b[co] + sum_{ci,a,c} in[ci,(y+1-a)/s,(x+1-c)/s] * w[ci,co,a,c]
// (valid, integer indices only).
// ---------------------------------------------------------------------------
__global__ __launch_bounds__(256, 4) void gen_kernel(
    const float* __restrict__ z, const int* __restrict__ g_idx,
    const float* __restrict__ W1, const float* __restrict__ b1,
    const float* __restrict__ W2, const float* __restrict__ b2,
    const float* __restrict__ cw1, const float* __restrict__ cb1,
    const float* __restrict__ cw2, const float* __restrict__ cb2,
    const float* __restrict__ cw3, const float* __restrict__ cb3,
    const int* __restrict__ wsi, float* __restrict__ out)
{
    __shared__ float zs[SPB][NZ];                     // 2 KB
    __shared__ float h1s[SPB][256];                   // 4 KB
    __shared__ __align__(16) u16 h2p[SPB][32][7][8];  // 14 KB (bf16, x padded 7->8)
    __shared__ __align__(16) u16 c1p[16][14][16];     // 7 KB  (bf16, x padded 14->16)
    __shared__ __align__(16) u16 c2p[8][28][28];      // 12.25 KB (bf16)
    __shared__ float w3s[72];
    __shared__ int sb[SPB];
    __shared__ int sV, sG;

    const int tid = threadIdx.x;
    const int base = blockIdx.x * SPB;
    const int total = wsi[0];
    if (base >= total) return;

    if (tid == 0) {
        int v = 0;
        for (int s = 0; s < SPB; ++s) {
            int e = wsi[16 + base + s];
            sb[s] = e;
            if (e >= 0) ++v;
        }
        sV = v;
        sG = g_idx[wsi[16 + base]];   // first slot of a chunk is always valid
    }
    __syncthreads();
    const int g = sG;
    const int V = sV;
    const float* W1g  = W1  + g * (NZ * 256);
    const float* b1g  = b1  + g * 256;
    const float* W2g  = W2  + g * (256 * 1568);
    const float* b2g  = b2  + g * 1568;
    const float* cw1g = cw1 + g * 8192;
    const float* cb1g = cb1 + g * 16;
    const float* cw2g = cw2 + g * 2048;
    const float* cb2g = cb2 + g * 8;
    const float* cw3g = cw3 + g * 72;
    const float  cb3v = cb3[g];

    // stage z (zero-fill padded samples) + conv3 weights
    for (int i = tid; i < SPB * NZ; i += 256) {
        int s = i >> 7, k = i & 127;
        zs[s][k] = (s < V) ? z[(size_t)sb[s] * NZ + k] : 0.f;
    }
    if (tid < 72) w3s[tid] = cw3g[tid];
    __syncthreads();

    // ---------------- FC1: [128] @ [128,256] -> h1[256] ----------------
    {
        float acc[SPB];
        const float bv = b1g[tid];
        #pragma unroll
        for (int s = 0; s < SPB; ++s) acc[s] = bv;
        for (int k = 0; k < NZ; ++k) {
            const float w = W1g[k * 256 + tid];
            #pragma unroll
            for (int s = 0; s < SPB; ++s) acc[s] += zs[s][k] * w;
        }
        #pragma unroll
        for (int s = 0; s < SPB; ++s) h1s[s][tid] = lrelu(acc[s]);
    }
    __syncthreads();

    // ---------------- FC2: [256] @ [256,1568] -> h2 (bf16 LDS) ----------------
    {
        float acc[7][SPB];
        #pragma unroll
        for (int c = 0; c < 7; ++c)
            #pragma unroll
            for (int s = 0; s < SPB; ++s) acc[c][s] = 0.f;
        const bool tail = (tid < 32);   // 1568 = 6*256 + 32
        const float* wp = W2g + tid;
        for (int k = 0; k < 256; ++k) {
            float hv[SPB];
            #pragma unroll
            for (int s = 0; s < SPB; ++s) hv[s] = h1s[s][k];
            #pragma unroll
            for (int c = 0; c < 7; ++c) {
                const float w = (c < 6 || tail) ? wp[c * 256] : 0.f;
                #pragma unroll
                for (int s = 0; s < SPB; ++s) acc[c][s] += hv[s] * w;
            }
            wp += 1568;
        }
        #pragma unroll
        for (int c = 0; c < 7; ++c) {
            const int j = tid + c * 256;
            if (j < 1568) {
                const float bv = b2g[j];
                const int ci = j / 49, rem = j % 49;
                const int iy = rem / 7, ix = rem % 7;
                #pragma unroll
                for (int s = 0; s < SPB; ++s)
                    h2p[s][ci][iy][ix] = f2bf(lrelu(acc[c][s] + bv));
            }
        }
    }
    __syncthreads();

    // ---------------- per-sample convs ----------------
    for (int s = 0; s < V; ++s) {
        // conv1: [32,7,7] -> [16,14,14], k=4, s=2, p=1
        if (tid < 224) {
            const int co = tid / 14, y = tid % 14;
            float acc[14];
            const float bv = cb1g[co];
            #pragma unroll
            for (int x = 0; x < 14; ++x) acc[x] = bv;
            const int a0 = (y + 1) & 1;
            for (int aa = 0; aa < 2; ++aa) {
                const int a = a0 + 2 * aa;
                const int iy = (y + 1 - a) >> 1;
                if ((unsigned)iy < 7u) {
                    for (int ci = 0; ci < 32; ++ci) {
                        float rr[8];
                        unpack8(&h2p[s][ci][iy][0], rr);
                        const float4 w4 = *(const float4*)(cw1g + ci * 256 + co * 16 + a * 4);
                        const float wv[4] = {w4.x, w4.y, w4.z, w4.w};
                        #pragma unroll
                        for (int x = 0; x < 14; ++x) {
                            const int c0v = (x + 1) & 1;
                            const int ix0 = (x + 1 - c0v) >> 1;
                            if (ix0 < 7)  acc[x] += rr[ix0] * wv[c0v];
                            if (ix0 >= 1) acc[x] += rr[ix0 - 1] * wv[c0v + 2];
                        }
                    }
                }
            }
            u32* dst = (u32*)&c1p[co][y][0];
            #pragma unroll
            for (int xx = 0; xx < 7; ++xx) {
                const u32 lo = f2bf(lrelu(acc[2 * xx]));
                const u32 hi = f2bf(lrelu(acc[2 * xx + 1]));
                dst[xx] = lo | (hi << 16);
            }
        }
        __syncthreads();

        // conv2: [16,14,14] -> [8,28,28], k=4, s=2, p=1
        if (tid < 224) {
            const int co = tid / 28, y = tid % 28;
            float acc[28];
            const float bv = cb2g[co];
            #pragma unroll
            for (int x = 0; x < 28; ++x) acc[x] = bv;
            const int a0 = (y + 1) & 1;
            for (int aa = 0; aa < 2; ++aa) {
                const int a = a0 + 2 * aa;
                const int iy = (y + 1 - a) >> 1;
                if ((unsigned)iy < 14u) {
                    for (int ci = 0; ci < 16; ++ci) {
                        float rr[16];
                        unpack8(&c1p[ci][iy][0], rr);
                        unpack8(&c1p[ci][iy][8], rr + 8);
                        const float4 w4 = *(const float4*)(cw2g + ci * 128 + co * 16 + a * 4);
                        const float wv[4] = {w4.x, w4.y, w4.z, w4.w};
                        #pragma unroll
                        for (int x = 0; x < 28; ++x) {
                            const int c0v = (x + 1) & 1;
                            const int ix0 = (x + 1 - c0v) >> 1;
                            if (ix0 < 14) acc[x] += rr[ix0] * wv[c0v];
                            if (ix0 >= 1) acc[x] += rr[ix0 - 1] * wv[c0v + 2];
                        }
                    }
                }
            }
            u32* dst = (u32*)&c2p[co][y][0];
            #pragma unroll
            for (int xx = 0; xx < 14; ++xx) {
                const u32 lo = f2bf(lrelu(acc[2 * xx]));
                const u32 hi = f2bf(lrelu(acc[2 * xx + 1]));
                dst[xx] = lo | (hi << 16);
            }
        }
        __syncthreads();

        // conv3: [8,28,28] -> [1,28,28], k=3, s=1, p=1, tanh
        if (tid < 196) {
            const int y = tid / 7, q = tid % 7;
            const int xb = q * 4;
            float acc[4] = {cb3v, cb3v, cb3v, cb3v};
            for (int ci = 0; ci < 8; ++ci) {
                float wv[9];
                #pragma unroll
                for (int j = 0; j < 9; ++j) wv[j] = w3s[ci * 9 + j];
                #pragma unroll
                for (int a = 0; a < 3; ++a) {
                    const int iy = y + 1 - a;
                    if ((unsigned)iy < 28u) {
                        float rr[6];
                        #pragma unroll
                        for (int j = 0; j < 6; ++j) {
                            const int ix = xb - 1 + j;
                            rr[j] = ((unsigned)ix < 28u) ? bf1(c2p[ci][iy][ix]) : 0.f;
                        }
                        #pragma unroll
                        for (int xx = 0; xx < 4; ++xx)
                            #pragma unroll
                            for (int c = 0; c < 3; ++c)
                                acc[xx] += rr[xx + 2 - c] * wv[a * 3 + c];
                    }
                }
            }
            float* op = out + (size_t)sb[s] * 784 + y * 28 + xb;
            #pragma unroll
            for (int xx = 0; xx < 4; ++xx) op[xx] = tanhf(acc[xx]);
        }
        __syncthreads();
    }
}

extern "C" void kernel_launch(void* const* d_in, const int* in_sizes, int n_in,
                              void* d_out, int out_size, void* d_ws, size_t ws_size,
                              hipStream_t stream) {
    const float* z   = (const float*)d_in[0];
    const int*   gi  = (const int*)d_in[1];
    const float* W1  = (const float*)d_in[2];
    const float* b1  = (const float*)d_in[3];
    const float* W2  = (const float*)d_in[4];
    const float* b2  = (const float*)d_in[5];
    const float* cw1 = (const float*)d_in[6];
    const float* cb1 = (const float*)d_in[7];
    const float* cw2 = (const float*)d_in[8];
    const float* cb2 = (const float*)d_in[9];
    const float* cw3 = (const float*)d_in[10];
    const float* cb3 = (const float*)d_in[11];
    int* wsi = (int*)d_ws;

    bin_kernel<<<1, 256, 0, stream>>>(gi, wsi);
    gen_kernel<<<NBLK, 256, 0, stream>>>(z, gi, W1, b1, W2, b2,
                                         cw1, cb1, cw2, cb2, cw3, cb3,
                                         wsi, (float*)d_out);
}